// Round 11
// baseline (6596.570 us; speedup 1.0000x reference)
//
#include <hip/hip_runtime.h>
#include <cstdint>
#include <cmath>

typedef unsigned short u16;
typedef unsigned int u32;
typedef unsigned long long u64;
typedef __attribute__((ext_vector_type(8))) short bf16x8;
typedef __attribute__((ext_vector_type(4))) float f32x4;

// ---- model dims ----
#define B_    8
#define T_IN  2048
#define CIN1  273
#define L1_   1025
#define L_    513
#define C_    512
#define CE_   576
#define M1_   (B_*L1_)   /* 8200 */
#define M_    (B_*L_)    /* 4104 */
#define K1_   (CIN1*4)   /* 1092 */
#define H_    8
#define D_    64
#define R_    50

__device__ __forceinline__ u32 f2bf_rne(float f) {
    u32 x = __float_as_uint(f);
    return (x + 0x7fffu + ((x >> 16) & 1u)) >> 16;
}

// ======================= A-element loader =======================
__device__ __forceinline__ float a_load(const void* A, int m, int k, int lda, int amode) {
    if (amode == 0) {
        return ((const float*)A)[(size_t)m * lda + k];
    } else if (amode == 2) {
        int b = m / L1_, t = m - b * L1_;
        int ci = k >> 2, kk = k & 3;
        int it = 2 * t - 2 + kk;
        if ((unsigned)it >= (unsigned)T_IN) return 0.f;
        return ((const float*)A)[((size_t)(b * CIN1 + ci)) * T_IN + it];
    } else if (amode == 3) {
        int b = m / L_, t = m - b * L_;
        int ci = k >> 2, kk = k & 3;
        int it = 2 * t - 2 + kk;
        if ((unsigned)it >= (unsigned)L1_) return 0.f;
        return ((const float*)A)[((size_t)(b * L1_ + it)) * C_ + ci];
    } else {
        int b = m / L_, t = m - b * L_;
        return ((const float*)A)[((size_t)(t * 8 + b)) * C_ + k];
    }
}

// ======================= MFMA GEMM =======================
__global__ __launch_bounds__(256) void gemm_kernel(
    const void* __restrict__ Aptr, const float* __restrict__ Bptr,
    const float* __restrict__ bias1, const float* __restrict__ bias2,
    float* __restrict__ Cf,
    int Msz, int Nsz, int Ksz, int lda, int ldc, int amode, int cmode, int relu)
{
    __shared__ u16 As[64][40];
    __shared__ u16 Bs[64][40];

    int tid = threadIdx.x;
    int m0 = blockIdx.x * 64, n0 = blockIdx.y * 64;
    int wv = tid >> 6, lane = tid & 63;
    int lm = lane & 15, quad = lane >> 4;
    int kp = tid & 15, rw = tid >> 4;

    f32x4 acc[4];
#pragma unroll
    for (int nt = 0; nt < 4; ++nt)
#pragma unroll
        for (int r = 0; r < 4; ++r) acc[nt][r] = 0.f;

    for (int k0 = 0; k0 < Ksz; k0 += 32) {
#pragma unroll
        for (int i = 0; i < 4; ++i) {
            int row = rw + 16 * i;
            int k = k0 + 2 * kp;
            int m = m0 + row;
            float a0 = 0.f, a1 = 0.f;
            if (m < Msz) {
                if (k < Ksz)     a0 = a_load(Aptr, m, k, lda, amode);
                if (k + 1 < Ksz) a1 = a_load(Aptr, m, k + 1, lda, amode);
            }
            *(u32*)&As[row][2 * kp] = f2bf_rne(a0) | (f2bf_rne(a1) << 16);
            int n = n0 + row;
            float b0 = 0.f, b1 = 0.f;
            if (k < Ksz)     b0 = Bptr[(size_t)n * Ksz + k];
            if (k + 1 < Ksz) b1 = Bptr[(size_t)n * Ksz + k + 1];
            *(u32*)&Bs[row][2 * kp] = f2bf_rne(b0) | (f2bf_rne(b1) << 16);
        }
        __syncthreads();

        bf16x8 af = *(const bf16x8*)&As[wv * 16 + lm][quad * 8];
#pragma unroll
        for (int nt = 0; nt < 4; ++nt) {
            bf16x8 bf = *(const bf16x8*)&Bs[nt * 16 + lm][quad * 8];
            acc[nt] = __builtin_amdgcn_mfma_f32_16x16x32_bf16(af, bf, acc[nt], 0, 0, 0);
        }
        __syncthreads();
    }

#pragma unroll
    for (int nt = 0; nt < 4; ++nt) {
#pragma unroll
        for (int r = 0; r < 4; ++r) {
            int m = m0 + wv * 16 + quad * 4 + r;
            if (m >= Msz) continue;
            int n = n0 + nt * 16 + lm;
            float v = acc[nt][r] + bias1[n] + (bias2 ? bias2[n] : 0.f);
            if (relu) v = fmaxf(v, 0.f);
            if (cmode == 0) {
                Cf[(size_t)m * ldc + n] = v;
            } else if (cmode == 1) {
                int b = m / L_, t = m - b * L_;
                Cf[((size_t)(b * 128 + n)) * L_ + t] = v;
            } else {
                int b = m / L_, t = m - b * L_;
                Cf[((size_t)(t * 8 + b)) * ldc + n] = v;
            }
        }
    }
}

// ======================= fused q/k/cnt projection GEMM =======================
__global__ __launch_bounds__(256) void gemm_qkv(
    const float* __restrict__ h1tm,
    const float* __restrict__ qw, const float* __restrict__ kw, const float* __restrict__ cw,
    const float* __restrict__ qb, const float* __restrict__ kb, const float* __restrict__ cb,
    float* __restrict__ qo, float* __restrict__ ko, float* __restrict__ co)
{
    __shared__ u16 As[64][40];
    __shared__ u16 Bs[64][40];

    int tid = threadIdx.x;
    int which = blockIdx.y >> 3;
    int m0 = blockIdx.x * 64, n0 = (blockIdx.y & 7) * 64;
    const float* Bptr = which == 0 ? qw : (which == 1 ? kw : cw);
    const float* bias = which == 0 ? qb : (which == 1 ? kb : cb);
    float* Cf = which == 0 ? qo : (which == 1 ? ko : co);

    int wv = tid >> 6, lane = tid & 63;
    int lm = lane & 15, quad = lane >> 4;
    int kp = tid & 15, rw = tid >> 4;

    f32x4 acc[4];
#pragma unroll
    for (int nt = 0; nt < 4; ++nt)
#pragma unroll
        for (int r = 0; r < 4; ++r) acc[nt][r] = 0.f;

    for (int k0 = 0; k0 < 512; k0 += 32) {
#pragma unroll
        for (int i = 0; i < 4; ++i) {
            int row = rw + 16 * i;
            int k = k0 + 2 * kp;
            int m = m0 + row;
            float a0 = 0.f, a1 = 0.f;
            if (m < M_) {
                int b = m / L_, t = m - b * L_;
                const float* ap = &h1tm[((size_t)(t * 8 + b)) * C_ + k];
                a0 = ap[0]; a1 = ap[1];
            }
            *(u32*)&As[row][2 * kp] = f2bf_rne(a0) | (f2bf_rne(a1) << 16);
            int n = n0 + row;
            float b0 = Bptr[(size_t)n * 512 + k];
            float b1 = Bptr[(size_t)n * 512 + k + 1];
            *(u32*)&Bs[row][2 * kp] = f2bf_rne(b0) | (f2bf_rne(b1) << 16);
        }
        __syncthreads();

        bf16x8 af = *(const bf16x8*)&As[wv * 16 + lm][quad * 8];
#pragma unroll
        for (int nt = 0; nt < 4; ++nt) {
            bf16x8 bf = *(const bf16x8*)&Bs[nt * 16 + lm][quad * 8];
            acc[nt] = __builtin_amdgcn_mfma_f32_16x16x32_bf16(af, bf, acc[nt], 0, 0, 0);
        }
        __syncthreads();
    }

#pragma unroll
    for (int nt = 0; nt < 4; ++nt) {
#pragma unroll
        for (int r = 0; r < 4; ++r) {
            int m = m0 + wv * 16 + quad * 4 + r;
            if (m >= M_) continue;
            int n = n0 + nt * 16 + lm;
            Cf[(size_t)m * 512 + n] = acc[nt][r] + bias[n];
        }
    }
}

// ======================= subject embedding concat =======================
__global__ __launch_bounds__(256) void emb_kernel(const float* __restrict__ semb,
                                                  const int* __restrict__ subj,
                                                  float* __restrict__ x2bt)
{
    int idx = blockIdx.x * 256 + threadIdx.x;
    if (idx >= M_ * 64) return;
    int m = idx >> 6, e = idx & 63;
    int b = m / L_;
    x2bt[(size_t)m * CE_ + 512 + e] = semb[subj[b] * 64 + e];
}

// ======================= weight pack: fp32 [2048][512] -> bf16x2 u32 =======================
__global__ __launch_bounds__(256) void pack_w(const float* __restrict__ W, u32* __restrict__ P)
{
    int gid = blockIdx.x * 256 + threadIdx.x;   // 524288 total
    int r = gid & 1, lane = (gid >> 1) & 63, i2 = (gid >> 7) & 1;
    int g = (gid >> 8) & 3, j = gid >> 10;
    int row = g * 512 + j;
    int c0 = 4 * (lane + 64 * i2) + 2 * r;
    u32 lo = f2bf_rne(W[(size_t)row * 512 + c0]);
    u32 hi = f2bf_rne(W[(size_t)row * 512 + c0 + 1]);
    P[gid] = lo | (hi << 16);
}

// ======================= 2-step fused LSTM launch =======================
// Launch ip = 0..256. Blocks 0..127: layer0 steps sA=2ip, sB=2ip+1.
// Blocks 128..255: layer1 steps sA=2ip-1, sB=2ip (lag 1).
// Phase A consumes only previous-launch data (normal loads); publishes h via
// relaxed agent atomic stores (LLC-bypass). One arrival counter + tid0 spin.
// Phase B consumes phase-A h via relaxed agent atomic loads (LLC). Weights
// register-cached once per launch, reused both phases. c crosses phases in LDS.
__global__ __launch_bounds__(256, 1) void lstm_step2(
    const float* __restrict__ pre0,
    const u32* __restrict__ P0,    // Whh0 packed
    const u32* __restrict__ P1,    // Wih1 packed
    const u32* __restrict__ P2,    // Whh1 packed
    const float* __restrict__ bih1,
    const float* __restrict__ bhh1,
    float* __restrict__ h0seq,
    float* __restrict__ h1seq,
    float* __restrict__ c0st, float* __restrict__ c1st,
    u32* __restrict__ flags, int ip)
{
    int layer = blockIdx.x >> 7;
    int blk = blockIdx.x & 127;
    int tid = threadIdx.x;
    int l = tid & 63, rg = tid >> 6;
    int j = blk * 4 + rg;
    int sA = layer ? (2 * ip - 1) : (2 * ip);
    int sB = sA + 1;
    bool validA = (sA >= 0) && (sA < L_);
    bool validB = (sB >= 0) && (sB < L_);

    __shared__ float4 hA4[1024];
    __shared__ float4 hB4[1024];
    __shared__ float part[4 * 8 * 33];
    __shared__ float gates[4 * 33];
    __shared__ float cl[4][8];

    float* hout = layer ? h1seq : h0seq;
    float* cst  = layer ? c1st : c0st;

    // ---- weights once (used by both phases) ----
    const u32* wAp = (layer ? P2 : P0) + (size_t)j * 1024;
    uint2 wra[8], wrb[8];
#pragma unroll
    for (int i2 = 0; i2 < 2; ++i2)
#pragma unroll
        for (int g = 0; g < 4; ++g)
            wra[i2 * 4 + g] = *(const uint2*)&wAp[(g * 2 + i2) * 128 + l * 2];
    if (layer) {
        const u32* wBp = P1 + (size_t)j * 1024;
#pragma unroll
        for (int i2 = 0; i2 < 2; ++i2)
#pragma unroll
            for (int g = 0; g < 4; ++g)
                wrb[i2 * 4 + g] = *(const uint2*)&wBp[(g * 2 + i2) * 128 + l * 2];
    }

    // ---- hoist additive terms for both phases (normal loads, old data) ----
    float preA = 0.f, preB = 0.f;
    if (tid < 128) {
        int fw = tid >> 5, fb = tid & 7;
        int grow = ((tid & 31) >> 3) * 512 + blk * 4 + fw;
        if (layer) { preA = bih1[grow] + bhh1[grow]; preB = preA; }
        else {
            if (validA) preA = pre0[((size_t)(sA * 8 + fb)) * 2048 + grow];
            if (validB) preB = pre0[((size_t)(sB * 8 + fb)) * 2048 + grow];
        }
    }
    float cprevA = 0.f;
    if (tid < 32 && validA && sA > 0)
        cprevA = cst[(tid & 7) * 512 + blk * 4 + (tid >> 3)];

    // =================== PHASE A ===================
    if (validA) {
        if (sA == 0) {
#pragma unroll
            for (int i = 0; i < 4; ++i) hA4[tid + 256 * i] = make_float4(0.f, 0.f, 0.f, 0.f);
        } else {
            const float4* src = (const float4*)((layer ? h1seq : h0seq) + (size_t)(sA - 1) * 4096);
#pragma unroll
            for (int i = 0; i < 4; ++i) hA4[tid + 256 * i] = src[tid + 256 * i];
        }
        if (layer) {
            const float4* src = (const float4*)(h0seq + (size_t)sA * 4096);
#pragma unroll
            for (int i = 0; i < 4; ++i) hB4[tid + 256 * i] = src[tid + 256 * i];
        }
        __syncthreads();

        float acc[4][8];
#pragma unroll
        for (int g = 0; g < 4; ++g)
#pragma unroll
            for (int b = 0; b < 8; ++b) acc[g][b] = 0.f;
#pragma unroll
        for (int i2 = 0; i2 < 2; ++i2) {
            int cq = l + 64 * i2;
            float4 hv[8];
#pragma unroll
            for (int b = 0; b < 8; ++b) hv[b] = hA4[b * 128 + cq];
#pragma unroll
            for (int g = 0; g < 4; ++g) {
                uint2 ww = wra[i2 * 4 + g];
                float w0 = __uint_as_float(ww.x << 16);
                float w1 = __uint_as_float(ww.x & 0xffff0000u);
                float w2 = __uint_as_float(ww.y << 16);
                float w3 = __uint_as_float(ww.y & 0xffff0000u);
#pragma unroll
                for (int b = 0; b < 8; ++b)
                    acc[g][b] = fmaf(w0, hv[b].x, fmaf(w1, hv[b].y,
                                fmaf(w2, hv[b].z, fmaf(w3, hv[b].w, acc[g][b]))));
            }
        }
        if (layer) {
#pragma unroll
            for (int i2 = 0; i2 < 2; ++i2) {
                int cq = l + 64 * i2;
                float4 hv[8];
#pragma unroll
                for (int b = 0; b < 8; ++b) hv[b] = hB4[b * 128 + cq];
#pragma unroll
                for (int g = 0; g < 4; ++g) {
                    uint2 ww = wrb[i2 * 4 + g];
                    float w0 = __uint_as_float(ww.x << 16);
                    float w1 = __uint_as_float(ww.x & 0xffff0000u);
                    float w2 = __uint_as_float(ww.y << 16);
                    float w3 = __uint_as_float(ww.y & 0xffff0000u);
#pragma unroll
                    for (int b = 0; b < 8; ++b)
                        acc[g][b] = fmaf(w0, hv[b].x, fmaf(w1, hv[b].y,
                                    fmaf(w2, hv[b].z, fmaf(w3, hv[b].w, acc[g][b]))));
                }
            }
        }
#pragma unroll
        for (int m = 8; m <= 32; m <<= 1)
#pragma unroll
            for (int g = 0; g < 4; ++g)
#pragma unroll
                for (int b = 0; b < 8; ++b)
                    acc[g][b] += __shfl_xor(acc[g][b], m);
        if (l < 8) {
#pragma unroll
            for (int g = 0; g < 4; ++g)
#pragma unroll
                for (int b = 0; b < 8; ++b)
                    part[(rg * 8 + l) * 33 + g * 8 + b] = acc[g][b];
        }
        __syncthreads();
        if (tid < 128) {
            int w = tid >> 5, x = tid & 31;
            float s = 0.f;
#pragma unroll
            for (int p = 0; p < 8; ++p) s += part[(w * 8 + p) * 33 + x];
            gates[w * 33 + x] = s + preA;
        }
        __syncthreads();
        if (tid < 32) {
            int w = tid >> 3, b = tid & 7;
            float gi = gates[w * 33 + 0 * 8 + b];
            float gf = gates[w * 33 + 1 * 8 + b];
            float gg = gates[w * 33 + 2 * 8 + b];
            float go = gates[w * 33 + 3 * 8 + b];
            float si = 1.f / (1.f + expf(-gi));
            float sf = 1.f / (1.f + expf(-gf));
            float so = 1.f / (1.f + expf(-go));
            float cn = sf * cprevA + si * tanhf(gg);
            cl[w][b] = cn;
            float hval = so * tanhf(cn);
            __hip_atomic_store((u32*)&hout[((size_t)sA * 8 + b) * 512 + blk * 4 + w],
                               __float_as_uint(hval), __ATOMIC_RELAXED, __HIP_MEMORY_SCOPE_AGENT);
        }
    }
    __syncthreads();

    // =================== handoff ===================
    if (tid == 0) {
        __hip_atomic_fetch_add(&flags[ip], 1u, __ATOMIC_RELEASE, __HIP_MEMORY_SCOPE_AGENT);
        long itc = 0;
        while (__hip_atomic_load(&flags[ip], __ATOMIC_RELAXED, __HIP_MEMORY_SCOPE_AGENT) < 256u) {
            __builtin_amdgcn_s_sleep(8);
            if (++itc > (1L << 30)) break;
        }
        (void)__hip_atomic_load(&flags[ip], __ATOMIC_ACQUIRE, __HIP_MEMORY_SCOPE_AGENT);
    }
    __syncthreads();

    // =================== PHASE B ===================
    if (validB) {
        if (sB == 0) {
#pragma unroll
            for (int i = 0; i < 4; ++i) hA4[tid + 256 * i] = make_float4(0.f, 0.f, 0.f, 0.f);
        } else {
            const u64* src = (const u64*)((layer ? h1seq : h0seq) + (size_t)(sB - 1) * 4096);
            u64* dst = (u64*)hA4;
#pragma unroll
            for (int q = 0; q < 8; ++q)
                dst[tid + 256 * q] = __hip_atomic_load(&src[tid + 256 * q],
                                                       __ATOMIC_RELAXED, __HIP_MEMORY_SCOPE_AGENT);
        }
        if (layer) {
            const u64* src = (const u64*)(h0seq + (size_t)sB * 4096);
            u64* dst = (u64*)hB4;
#pragma unroll
            for (int q = 0; q < 8; ++q)
                dst[tid + 256 * q] = __hip_atomic_load(&src[tid + 256 * q],
                                                       __ATOMIC_RELAXED, __HIP_MEMORY_SCOPE_AGENT);
        }
        __syncthreads();

        float acc[4][8];
#pragma unroll
        for (int g = 0; g < 4; ++g)
#pragma unroll
            for (int b = 0; b < 8; ++b) acc[g][b] = 0.f;
#pragma unroll
        for (int i2 = 0; i2 < 2; ++i2) {
            int cq = l + 64 * i2;
            float4 hv[8];
#pragma unroll
            for (int b = 0; b < 8; ++b) hv[b] = hA4[b * 128 + cq];
#pragma unroll
            for (int g = 0; g < 4; ++g) {
                uint2 ww = wra[i2 * 4 + g];
                float w0 = __uint_as_float(ww.x << 16);
                float w1 = __uint_as_float(ww.x & 0xffff0000u);
                float w2 = __uint_as_float(ww.y << 16);
                float w3 = __uint_as_float(ww.y & 0xffff0000u);
#pragma unroll
                for (int b = 0; b < 8; ++b)
                    acc[g][b] = fmaf(w0, hv[b].x, fmaf(w1, hv[b].y,
                                fmaf(w2, hv[b].z, fmaf(w3, hv[b].w, acc[g][b]))));
            }
        }
        if (layer) {
#pragma unroll
            for (int i2 = 0; i2 < 2; ++i2) {
                int cq = l + 64 * i2;
                float4 hv[8];
#pragma unroll
                for (int b = 0; b < 8; ++b) hv[b] = hB4[b * 128 + cq];
#pragma unroll
                for (int g = 0; g < 4; ++g) {
                    uint2 ww = wrb[i2 * 4 + g];
                    float w0 = __uint_as_float(ww.x << 16);
                    float w1 = __uint_as_float(ww.x & 0xffff0000u);
                    float w2 = __uint_as_float(ww.y << 16);
                    float w3 = __uint_as_float(ww.y & 0xffff0000u);
#pragma unroll
                    for (int b = 0; b < 8; ++b)
                        acc[g][b] = fmaf(w0, hv[b].x, fmaf(w1, hv[b].y,
                                    fmaf(w2, hv[b].z, fmaf(w3, hv[b].w, acc[g][b]))));
                }
            }
        }
#pragma unroll
        for (int m = 8; m <= 32; m <<= 1)
#pragma unroll
            for (int g = 0; g < 4; ++g)
#pragma unroll
                for (int b = 0; b < 8; ++b)
                    acc[g][b] += __shfl_xor(acc[g][b], m);
        if (l < 8) {
#pragma unroll
            for (int g = 0; g < 4; ++g)
#pragma unroll
                for (int b = 0; b < 8; ++b)
                    part[(rg * 8 + l) * 33 + g * 8 + b] = acc[g][b];
        }
        __syncthreads();
        if (tid < 128) {
            int w = tid >> 5, x = tid & 31;
            float s = 0.f;
#pragma unroll
            for (int p = 0; p < 8; ++p) s += part[(w * 8 + p) * 33 + x];
            gates[w * 33 + x] = s + preB;
        }
        __syncthreads();
        if (tid < 32) {
            int w = tid >> 3, b = tid & 7;
            float gi = gates[w * 33 + 0 * 8 + b];
            float gf = gates[w * 33 + 1 * 8 + b];
            float gg = gates[w * 33 + 2 * 8 + b];
            float go = gates[w * 33 + 3 * 8 + b];
            float cprev = (sB == 0) ? 0.f : cl[w][b];
            float si = 1.f / (1.f + expf(-gi));
            float sf = 1.f / (1.f + expf(-gf));
            float so = 1.f / (1.f + expf(-go));
            float cn = sf * cprev + si * tanhf(gg);
            int ji = blk * 4 + w;
            cst[b * 512 + ji] = cn;
            hout[((size_t)sB * 8 + b) * 512 + ji] = so * tanhf(cn);
        }
    }
}

// ======================= banded attention (radius 50) =======================
__global__ __launch_bounds__(128) void attn_kernel(const float* __restrict__ q,
                                                   const float* __restrict__ k,
                                                   const float* __restrict__ cnt,
                                                   const float* __restrict__ rel,
                                                   float* __restrict__ out)
{
    int t = blockIdx.x, h = blockIdx.y, b = blockIdx.z;
    int s_lo = max(0, t - R_), s_hi = min(L_ - 1, t + R_);
    int W = s_hi - s_lo + 1;
    int tid = threadIdx.x;

    __shared__ float qrow[64];
    __shared__ float dots[104];
    __shared__ float red[128];

    const float* qp = q + ((size_t)(b * L_ + t) * C_ + h * D_);
    if (tid < 64) qrow[tid] = qp[tid];
    __syncthreads();

    if (tid < W) {
        int s = s_lo + tid;
        const float* kp = k + ((size_t)(b * L_ + s) * C_ + h * D_);
        const float* rp = rel + (R_ + t - s) * D_;
        float acc = 0.f;
#pragma unroll 8
        for (int d = 0; d < 64; ++d)
            acc += qrow[d] * (kp[d] + 0.3f * rp[d]);
        dots[tid] = acc;
    }
    __syncthreads();

    red[tid] = (tid < W) ? dots[tid] : -INFINITY;
    __syncthreads();
    for (int s = 64; s > 0; s >>= 1) {
        if (tid < s) red[tid] = fmaxf(red[tid], red[tid + s]);
        __syncthreads();
    }
    float mx = red[0];
    __syncthreads();
    float e = 0.f;
    if (tid < W) { e = expf(dots[tid] - mx); dots[tid] = e; }
    red[tid] = e;
    __syncthreads();
    for (int s = 64; s > 0; s >>= 1) {
        if (tid < s) red[tid] += red[tid + s];
        __syncthreads();
    }
    float inv = 1.f / red[0];
    if (tid < W) dots[tid] *= inv;
    __syncthreads();

    if (tid < 64) {
        float acc = 0.f;
        const float* cb = cnt + ((size_t)(b * L_ + s_lo) * C_ + h * D_ + tid);
        const float* rb = rel + (R_ + t - s_lo) * D_ + tid;
        for (int i = 0; i < W; ++i)
            acc += dots[i] * (cb[(size_t)i * C_] + 0.3f * rb[-i * D_]);
        out[(size_t)(b * L_ + t) * C_ + h * D_ + tid] = acc;
    }
}

// ======================= BatchNorm training stats =======================
__global__ __launch_bounds__(256) void bn_stats(const float* __restrict__ fcout, float* __restrict__ stats)
{
    int o = blockIdx.x;
    int tid = threadIdx.x;
    float s = 0.f, ss = 0.f;
    for (int m = tid; m < M_; m += 256) {
        float v = fcout[(size_t)m * 512 + o];
        s += v; ss += v * v;
    }
    __shared__ float rs[256], rq[256];
    rs[tid] = s; rq[tid] = ss;
    __syncthreads();
    for (int k = 128; k > 0; k >>= 1) {
        if (tid < k) { rs[tid] += rs[tid + k]; rq[tid] += rq[tid + k]; }
        __syncthreads();
    }
    if (tid == 0) {
        float mean = rs[0] / (float)M_;
        float var = rq[0] / (float)M_ - mean * mean;
        stats[o] = mean;
        stats[512 + o] = rsqrtf(fmaxf(var, 0.f) + 1e-5f);
    }
}

// ======================= BN apply + ReLU*scale + residual =======================
__global__ __launch_bounds__(256) void bn_apply(const float* __restrict__ fcout,
                                                const float* __restrict__ stats,
                                                const float* __restrict__ bng, const float* __restrict__ bnb,
                                                const float* __restrict__ ascl,
                                                const float* __restrict__ h1tm,
                                                float* __restrict__ xfin)
{
    int idx = blockIdx.x * 256 + threadIdx.x;
    if (idx >= M_ * 512) return;
    int c = idx & 511;
    int m = idx >> 9;
    int b = m / L_, t = m - b * L_;
    float v = (fcout[idx] - stats[c]) * stats[512 + c] * bng[c] + bnb[c];
    v = fmaxf(v, 0.f) * ascl[c];
    xfin[idx] = h1tm[((size_t)(t * 8 + b)) * 512 + c] + v;
}

// ======================= host launch =======================
extern "C" void kernel_launch(void* const* d_in, const int* in_sizes, int n_in,
                              void* d_out, int out_size, void* d_ws, size_t ws_size,
                              hipStream_t stream)
{
    const float* meg  = (const float*)d_in[0];
    const float* w1   = (const float*)d_in[1];
    const float* b1   = (const float*)d_in[2];
    const float* w2   = (const float*)d_in[3];
    const float* b2   = (const float*)d_in[4];
    const float* semb = (const float*)d_in[5];
    const float* Wih0 = (const float*)d_in[6];
    const float* Whh0 = (const float*)d_in[7];
    const float* bih0 = (const float*)d_in[8];
    const float* bhh0 = (const float*)d_in[9];
    const float* Wih1 = (const float*)d_in[10];
    const float* Whh1 = (const float*)d_in[11];
    const float* bih1 = (const float*)d_in[12];
    const float* bhh1 = (const float*)d_in[13];
    const float* qw   = (const float*)d_in[14];
    const float* qb   = (const float*)d_in[15];
    const float* kw   = (const float*)d_in[16];
    const float* kb   = (const float*)d_in[17];
    const float* cw   = (const float*)d_in[18];
    const float* cbi  = (const float*)d_in[19];
    const float* rel  = (const float*)d_in[20];
    const float* fcw  = (const float*)d_in[21];
    const float* fcb  = (const float*)d_in[22];
    const float* bng  = (const float*)d_in[23];
    const float* bnb  = (const float*)d_in[24];
    const float* ascl = (const float*)d_in[25];
    const float* outw = (const float*)d_in[26];
    const float* outb = (const float*)d_in[27];
    const int* subj = (const int*)d_in[28];
    float* out = (float*)d_out;

    float* ws = (float*)d_ws;
    // arena (float offsets)
    float* x1    = ws + 0;          // [8200][512] conv phase only -> 4,198,400
    // LSTM-phase overlays of the dead x1 region:
    u32*   P0    = (u32*)(ws + 0);        // Whh0 bf16 packed: 524,288 words
    u32*   P1    = (u32*)(ws + 524288);   // Wih1
    u32*   P2    = (u32*)(ws + 1048576);  // Whh1
    float* c0    = ws + 1572864;    // [8][512] cell state L0
    float* c1    = ws + 1576960;    // [8][512] cell state L1
    u32*   flags = (u32*)(ws + 1581056);  // [260] arrival counters
    float* x2bt  = ws + 4198400;    // [4104][576]                 -> 6,562,304
    float* pre0  = ws + 6562304;    // [(t*8+b)][2048]             -> 14,967,296
    float* h0    = ws + 14967296;   // [t][b][c]                   -> 17,068,544
    float* h1    = ws + 17068544;   // [t][b][c]                   -> 19,169,792
    float* xfin  = ws + 19169792;   // [b*L+t][c] final residual   -> 21,271,040
    // post-LSTM overlays:
    float* qb_f  = ws + 0;          // q  [4104][512]
    float* kb_f  = ws + 2101248;    // k
    float* cb_f  = ws + 4202496;    // cnt (spills into dead x2bt region)
    float* attno = ws + 6562304;    // over pre0
    float* fco   = ws + 8663552;
    float* stats = ws + 10764800;   // 1024 floats

    auto gemm = [&](const void* A, const float* Bw, const float* bi1, const float* bi2,
                    float* Cf, int Msz, int Nsz, int Ksz,
                    int lda, int ldc, int amode, int cmode, int relu) {
        dim3 g((Msz + 63) / 64, Nsz / 64);
        gemm_kernel<<<g, 256, 0, stream>>>(A, Bw, bi1, bi2, Cf,
                                           Msz, Nsz, Ksz, lda, ldc, amode, cmode, relu);
    };

    // conv1 (im2col from meg) -> x1 [b*1025+t][512], relu
    gemm(meg, w1, b1, nullptr, x1, M1_, 512, K1_, 0, 512, 2, 0, 1);
    // conv2 (im2col from x1) -> x2bt [b*513+t][576] cols 0..511, relu
    gemm(x1, w2, b2, nullptr, x2bt, M_, 512, 2048, 0, CE_, 3, 0, 1);
    // subject embedding -> cols 512..575
    emb_kernel<<<(M_ * 64 + 255) / 256, 256, 0, stream>>>(semb, subj, x2bt);

    // pack LSTM weights to bf16 (x1 region is dead now)
    pack_w<<<2048, 256, 0, stream>>>(Whh0, P0);
    pack_w<<<2048, 256, 0, stream>>>(Wih1, P1);
    pack_w<<<2048, 256, 0, stream>>>(Whh1, P2);

    // zero arrival counters (capturable async memset)
    hipMemsetAsync(flags, 0, 260 * sizeof(u32), stream);

    // layer-0 x-projection (time-major output, both biases folded)
    gemm(x2bt, Wih0, bih0, bhh0, pre0, M_, 2048, CE_, CE_, 2048, 0, 2, 0);

    // 2-step fused LSTM: 257 launches
    for (int ip = 0; ip <= 256; ++ip)
        lstm_step2<<<256, 256, 0, stream>>>(pre0, P0, P1, P2, bih1, bhh1,
                                            h0, h1, c0, c1, flags, ip);

    // fused q/k/cnt projections (read h1 time-major)
    gemm_qkv<<<dim3((M_ + 63) / 64, 24), 256, 0, stream>>>(h1, qw, kw, cw, qb, kb, cbi,
                                                           qb_f, kb_f, cb_f);

    attn_kernel<<<dim3(L_, H_, B_), 128, 0, stream>>>(qb_f, kb_f, cb_f, rel, attno);

    // fc + BN(train) + relu*scale + residual -> xfin (batch-major)
    gemm(attno, fcw, fcb, nullptr, fco, M_, 512, 512, 512, 512, 0, 0, 0);
    bn_stats<<<512, 256, 0, stream>>>(fco, stats);
    bn_apply<<<(M_ * 512 + 255) / 256, 256, 0, stream>>>(fco, stats, bng, bnb, ascl, h1, xfin);

    // final projection -> d_out [b][128][t] fp32
    gemm(xfin, outw, outb, nullptr, out, M_, 128, 512, 512, 0, 0, 1, 0);
}

// Round 12
// 4361.713 us; speedup vs baseline: 1.5124x; 1.5124x over previous
//
#include <hip/hip_runtime.h>
#include <cstdint>
#include <cmath>

typedef unsigned short u16;
typedef unsigned int u32;
typedef __attribute__((ext_vector_type(8))) short bf16x8;
typedef __attribute__((ext_vector_type(4))) float f32x4;

// ---- model dims ----
#define B_    8
#define T_IN  2048
#define CIN1  273
#define L1_   1025
#define L_    513
#define C_    512
#define CE_   576
#define M1_   (B_*L1_)   /* 8200 */
#define M_    (B_*L_)    /* 4104 */
#define K1_   (CIN1*4)   /* 1092 */
#define H_    8
#define D_    64
#define R_    50

__device__ __forceinline__ u32 f2bf_rne(float f) {
    u32 x = __float_as_uint(f);
    return (x + 0x7fffu + ((x >> 16) & 1u)) >> 16;
}

// ======================= A-pair loader: returns packed bf16x2 for (k, k+1), k even ==============
// amode: 0 fp32 rowmajor(lda); 2 conv1 im2col from meg (fp32); 5 conv2 im2col from x1b (bf16,
//        k-order kk*512+ci); 6 bf16 rowmajor(lda); 7 bf16 time-major [t*8+b][512]
__device__ __forceinline__ u32 a_pair(const void* A, int m, int k, int lda, int amode, int Ksz) {
    if (amode == 0) {
        const float* Af = (const float*)A;
        u32 lo = (k < Ksz)     ? f2bf_rne(Af[(size_t)m * lda + k])     : 0;
        u32 hi = (k + 1 < Ksz) ? f2bf_rne(Af[(size_t)m * lda + k + 1]) : 0;
        return lo | (hi << 16);
    } else if (amode == 2) {
        if (k >= K1_) return 0;
        int b = m / L1_, t = m - b * L1_;
        int ci = k >> 2, kk = k & 3;          // pair = (kk, kk+1), same ci -> contiguous it
        int it = 2 * t - 2 + kk;
        const float* mg = (const float*)A + ((size_t)(b * CIN1 + ci)) * T_IN;
        u32 lo = ((unsigned)it < (unsigned)T_IN)       ? f2bf_rne(mg[it])     : 0;
        u32 hi = ((unsigned)(it + 1) < (unsigned)T_IN) ? f2bf_rne(mg[it + 1]) : 0;
        return lo | (hi << 16);
    } else if (amode == 5) {
        int b = m / L_, t = m - b * L_;
        int kk = k >> 9, ci = k & 511;        // pair = (ci, ci+1), same kk -> contiguous u32
        int it = 2 * t - 2 + kk;
        if ((unsigned)it >= (unsigned)L1_) return 0;
        return *(const u32*)((const u16*)A + ((size_t)(b * L1_ + it)) * 512 + ci);
    } else if (amode == 6) {
        return *(const u32*)((const u16*)A + (size_t)m * lda + k);
    } else {
        int b = m / L_, t = m - b * L_;
        return *(const u32*)((const u16*)A + ((size_t)(t * 8 + b)) * 512 + k);
    }
}

// ======================= MFMA GEMM (packed bf16 B) =======================
// cmode: 0 fp32 C[m*ldc+n]; 1 out[b][n][t] (n<128); 2 fp32 [(t*8+b)*ldc+n]; 3 bf16 Cb[m*ldc+n]
__global__ __launch_bounds__(256) void gemm_kernel(
    const void* __restrict__ Aptr, const u32* __restrict__ Bp,
    const float* __restrict__ bias1, const float* __restrict__ bias2,
    float* __restrict__ Cf, u16* __restrict__ Cb,
    int Msz, int Nsz, int Ksz, int lda, int ldc, int amode, int cmode, int relu)
{
    __shared__ u16 As[64][40];
    __shared__ u16 Bs[64][40];

    int tid = threadIdx.x;
    int m0 = blockIdx.x * 64, n0 = blockIdx.y * 64;
    int wv = tid >> 6, lane = tid & 63;
    int lm = lane & 15, quad = lane >> 4;
    int kp = tid & 15, rw = tid >> 4;
    int Kh = Ksz >> 1;

    f32x4 acc[4];
#pragma unroll
    for (int nt = 0; nt < 4; ++nt)
#pragma unroll
        for (int r = 0; r < 4; ++r) acc[nt][r] = 0.f;

    for (int k0 = 0; k0 < Ksz; k0 += 32) {
        int pidx = (k0 >> 1) + kp;
#pragma unroll
        for (int i = 0; i < 4; ++i) {
            int row = rw + 16 * i;
            int k = k0 + 2 * kp;
            int m = m0 + row;
            u32 aw = 0;
            if (m < Msz && k < Ksz) aw = a_pair(Aptr, m, k, lda, amode, Ksz);
            *(u32*)&As[row][2 * kp] = aw;
            u32 bw = 0;
            if (pidx < Kh) bw = Bp[(size_t)(n0 + row) * Kh + pidx];
            *(u32*)&Bs[row][2 * kp] = bw;
        }
        __syncthreads();

        bf16x8 af = *(const bf16x8*)&As[wv * 16 + lm][quad * 8];
#pragma unroll
        for (int nt = 0; nt < 4; ++nt) {
            bf16x8 bf = *(const bf16x8*)&Bs[nt * 16 + lm][quad * 8];
            acc[nt] = __builtin_amdgcn_mfma_f32_16x16x32_bf16(af, bf, acc[nt], 0, 0, 0);
        }
        __syncthreads();
    }

#pragma unroll
    for (int nt = 0; nt < 4; ++nt) {
#pragma unroll
        for (int r = 0; r < 4; ++r) {
            int m = m0 + wv * 16 + quad * 4 + r;
            if (m >= Msz) continue;
            int n = n0 + nt * 16 + lm;
            float v = acc[nt][r] + bias1[n] + (bias2 ? bias2[n] : 0.f);
            if (relu) v = fmaxf(v, 0.f);
            if (cmode == 0) {
                Cf[(size_t)m * ldc + n] = v;
            } else if (cmode == 1) {
                int b = m / L_, t = m - b * L_;
                Cf[((size_t)(b * 128 + n)) * L_ + t] = v;
            } else if (cmode == 2) {
                int b = m / L_, t = m - b * L_;
                Cf[((size_t)(t * 8 + b)) * ldc + n] = v;
            } else {
                Cb[(size_t)m * ldc + n] = (u16)f2bf_rne(v);
            }
        }
    }
}

// ======================= fused q/k/cnt projection GEMM (bf16 h1b A, packed B) ==================
__global__ __launch_bounds__(256) void gemm_qkv(
    const u16* __restrict__ h1b,
    const u32* __restrict__ qwp, const u32* __restrict__ kwp, const u32* __restrict__ cwp,
    const float* __restrict__ qb, const float* __restrict__ kb, const float* __restrict__ cb,
    float* __restrict__ qo, float* __restrict__ ko, float* __restrict__ co)
{
    __shared__ u16 As[64][40];
    __shared__ u16 Bs[64][40];

    int tid = threadIdx.x;
    int which = blockIdx.y >> 3;
    int m0 = blockIdx.x * 64, n0 = (blockIdx.y & 7) * 64;
    const u32* Bp = which == 0 ? qwp : (which == 1 ? kwp : cwp);
    const float* bias = which == 0 ? qb : (which == 1 ? kb : cb);
    float* Cf = which == 0 ? qo : (which == 1 ? ko : co);

    int wv = tid >> 6, lane = tid & 63;
    int lm = lane & 15, quad = lane >> 4;
    int kp = tid & 15, rw = tid >> 4;

    f32x4 acc[4];
#pragma unroll
    for (int nt = 0; nt < 4; ++nt)
#pragma unroll
        for (int r = 0; r < 4; ++r) acc[nt][r] = 0.f;

    for (int k0 = 0; k0 < 512; k0 += 32) {
#pragma unroll
        for (int i = 0; i < 4; ++i) {
            int row = rw + 16 * i;
            int k = k0 + 2 * kp;
            int m = m0 + row;
            u32 aw = 0;
            if (m < M_) {
                int b = m / L_, t = m - b * L_;
                aw = *(const u32*)(h1b + ((size_t)(t * 8 + b)) * 512 + k);
            }
            *(u32*)&As[row][2 * kp] = aw;
            *(u32*)&Bs[row][2 * kp] = Bp[(size_t)(n0 + row) * 256 + (k0 >> 1) + kp];
        }
        __syncthreads();

        bf16x8 af = *(const bf16x8*)&As[wv * 16 + lm][quad * 8];
#pragma unroll
        for (int nt = 0; nt < 4; ++nt) {
            bf16x8 bf = *(const bf16x8*)&Bs[nt * 16 + lm][quad * 8];
            acc[nt] = __builtin_amdgcn_mfma_f32_16x16x32_bf16(af, bf, acc[nt], 0, 0, 0);
        }
        __syncthreads();
    }

#pragma unroll
    for (int nt = 0; nt < 4; ++nt) {
#pragma unroll
        for (int r = 0; r < 4; ++r) {
            int m = m0 + wv * 16 + quad * 4 + r;
            if (m >= M_) continue;
            int n = n0 + nt * 16 + lm;
            Cf[(size_t)m * 512 + n] = acc[nt][r] + bias[n];
        }
    }
}

// ======================= subject embedding concat (bf16) =======================
__global__ __launch_bounds__(256) void emb_kernel(const float* __restrict__ semb,
                                                  const int* __restrict__ subj,
                                                  u16* __restrict__ x2b)
{
    int idx = blockIdx.x * 256 + threadIdx.x;
    if (idx >= M_ * 64) return;
    int m = idx >> 6, e = idx & 63;
    int b = m / L_;
    x2b[(size_t)m * CE_ + 512 + e] = (u16)f2bf_rne(semb[subj[b] * 64 + e]);
}

// ======================= generic weight pack: fp32 [N][K] -> bf16 pairs [N][K/2] ================
__global__ __launch_bounds__(256) void pack_b(const float* __restrict__ W, u32* __restrict__ P,
                                              int N, int K)
{
    int gid = blockIdx.x * 256 + threadIdx.x;
    int Kh = K >> 1;
    if (gid >= N * Kh) return;
    int n = gid / Kh, p = gid - n * Kh;
    int k = 2 * p;
    u32 lo = f2bf_rne(W[(size_t)n * K + k]);
    u32 hi = f2bf_rne(W[(size_t)n * K + k + 1]);
    P[gid] = lo | (hi << 16);
}

// ======================= w2 pack with k-reorder: k' = kk*512 + ci =======================
// P[n][k'/2]: pair = (w2[n][ci*4+kk], w2[n][(ci+1)*4+kk])
__global__ __launch_bounds__(256) void pack_w2k(const float* __restrict__ W, u32* __restrict__ P)
{
    int gid = blockIdx.x * 256 + threadIdx.x;   // 512*1024
    int n = gid >> 10, p = gid & 1023;
    int kk = p >> 8, ci = (2 * p) & 511;
    u32 lo = f2bf_rne(W[(size_t)n * 2048 + ci * 4 + kk]);
    u32 hi = f2bf_rne(W[(size_t)n * 2048 + ci * 4 + 4 + kk]);
    P[gid] = lo | (hi << 16);
}

// ======================= LSTM weight pack (unchanged layout) =======================
__global__ __launch_bounds__(256) void pack_w(const float* __restrict__ W, u32* __restrict__ P)
{
    int gid = blockIdx.x * 256 + threadIdx.x;   // 524288 total
    int r = gid & 1, lane = (gid >> 1) & 63, i2 = (gid >> 7) & 1;
    int g = (gid >> 8) & 3, j = gid >> 10;
    int row = g * 512 + j;
    int c0 = 4 * (lane + 64 * i2) + 2 * r;
    u32 lo = f2bf_rne(W[(size_t)row * 512 + c0]);
    u32 hi = f2bf_rne(W[(size_t)row * 512 + c0 + 1]);
    P[gid] = lo | (hi << 16);
}

// ======================= fused 2-layer LSTM step (R10 structure + h1b mirror) ==================
__global__ __launch_bounds__(256, 1) void lstm_step_fused(
    const float* __restrict__ pre0,
    const u32* __restrict__ P0,
    const u32* __restrict__ P1,
    const u32* __restrict__ P2,
    const float* __restrict__ bih1,
    const float* __restrict__ bhh1,
    float* __restrict__ h0seq,
    float* __restrict__ h1seq,
    u16* __restrict__ h1b,
    float* __restrict__ c0st, float* __restrict__ c1st,
    int t)
{
    int layer = blockIdx.x >> 7;
    int blk = blockIdx.x & 127;
    if (layer == 0 && t >= L_) return;
    if (layer == 1 && t == 0) return;
    int tt = layer ? (t - 1) : t;

    int tid = threadIdx.x;
    int l  = tid & 63;
    int rg = tid >> 6;
    int j = blk * 4 + rg;

    __shared__ float4 hA4[1024];
    __shared__ float4 hB4[1024];
    __shared__ float part[4 * 8 * 33];
    __shared__ float gates[4 * 33];

    const u32* wA = (layer ? P2 : P0) + (size_t)j * 1024;
    uint2 wra[8], wrb[8];
#pragma unroll
    for (int i2 = 0; i2 < 2; ++i2)
#pragma unroll
        for (int g = 0; g < 4; ++g)
            wra[i2 * 4 + g] = *(const uint2*)&wA[(g * 2 + i2) * 128 + l * 2];
    if (layer) {
        const u32* wB = P1 + (size_t)j * 1024;
#pragma unroll
        for (int i2 = 0; i2 < 2; ++i2)
#pragma unroll
            for (int g = 0; g < 4; ++g)
                wrb[i2 * 4 + g] = *(const uint2*)&wB[(g * 2 + i2) * 128 + l * 2];
    }
    float mypre = 0.f;
    if (tid < 128) {
        int fw = tid >> 5, fb = tid & 7;
        int grow = ((tid & 31) >> 3) * 512 + blk * 4 + fw;
        mypre = layer ? (bih1[grow] + bhh1[grow])
                      : pre0[((size_t)(tt * 8 + fb)) * 2048 + grow];
    }

    if (tt == 0) {
#pragma unroll
        for (int i = 0; i < 4; ++i)
            hA4[tid + 256 * i] = make_float4(0.f, 0.f, 0.f, 0.f);
    } else {
        const float4* src = (const float4*)((layer ? h1seq : h0seq) + (size_t)(tt - 1) * 4096);
#pragma unroll
        for (int i = 0; i < 4; ++i)
            hA4[tid + 256 * i] = src[tid + 256 * i];
    }
    if (layer) {
        const float4* src = (const float4*)(h0seq + (size_t)tt * 4096);
#pragma unroll
        for (int i = 0; i < 4; ++i)
            hB4[tid + 256 * i] = src[tid + 256 * i];
    }
    __syncthreads();

    float acc[4][8];
#pragma unroll
    for (int g = 0; g < 4; ++g)
#pragma unroll
        for (int b = 0; b < 8; ++b) acc[g][b] = 0.f;

#pragma unroll
    for (int i2 = 0; i2 < 2; ++i2) {
        int cq = l + 64 * i2;
        float4 hv[8];
#pragma unroll
        for (int b = 0; b < 8; ++b) hv[b] = hA4[b * 128 + cq];
#pragma unroll
        for (int g = 0; g < 4; ++g) {
            uint2 ww = wra[i2 * 4 + g];
            float w0 = __uint_as_float(ww.x << 16);
            float w1 = __uint_as_float(ww.x & 0xffff0000u);
            float w2 = __uint_as_float(ww.y << 16);
            float w3 = __uint_as_float(ww.y & 0xffff0000u);
#pragma unroll
            for (int b = 0; b < 8; ++b)
                acc[g][b] = fmaf(w0, hv[b].x, fmaf(w1, hv[b].y,
                            fmaf(w2, hv[b].z, fmaf(w3, hv[b].w, acc[g][b]))));
        }
    }
    if (layer) {
#pragma unroll
        for (int i2 = 0; i2 < 2; ++i2) {
            int cq = l + 64 * i2;
            float4 hv[8];
#pragma unroll
            for (int b = 0; b < 8; ++b) hv[b] = hB4[b * 128 + cq];
#pragma unroll
            for (int g = 0; g < 4; ++g) {
                uint2 ww = wrb[i2 * 4 + g];
                float w0 = __uint_as_float(ww.x << 16);
                float w1 = __uint_as_float(ww.x & 0xffff0000u);
                float w2 = __uint_as_float(ww.y << 16);
                float w3 = __uint_as_float(ww.y & 0xffff0000u);
#pragma unroll
                for (int b = 0; b < 8; ++b)
                    acc[g][b] = fmaf(w0, hv[b].x, fmaf(w1, hv[b].y,
                                fmaf(w2, hv[b].z, fmaf(w3, hv[b].w, acc[g][b]))));
            }
        }
    }

#pragma unroll
    for (int m = 8; m <= 32; m <<= 1)
#pragma unroll
        for (int g = 0; g < 4; ++g)
#pragma unroll
            for (int b = 0; b < 8; ++b)
                acc[g][b] += __shfl_xor(acc[g][b], m);
    if (l < 8) {
#pragma unroll
        for (int g = 0; g < 4; ++g)
#pragma unroll
            for (int b = 0; b < 8; ++b)
                part[(rg * 8 + l) * 33 + g * 8 + b] = acc[g][b];
    }
    __syncthreads();

    if (tid < 128) {
        int w = tid >> 5, x = tid & 31;
        float s = 0.f;
#pragma unroll
        for (int p = 0; p < 8; ++p) s += part[(w * 8 + p) * 33 + x];
        gates[w * 33 + x] = s + mypre;
    }
    __syncthreads();

    if (tid < 32) {
        int w = tid >> 3, b = tid & 7;
        float gi = gates[w * 33 + 0 * 8 + b];
        float gf = gates[w * 33 + 1 * 8 + b];
        float gg = gates[w * 33 + 2 * 8 + b];
        float go = gates[w * 33 + 3 * 8 + b];
        float* cst = layer ? c1st : c0st;
        int ji = blk * 4 + w;
        int ci = b * 512 + ji;
        float cprev = (tt == 0) ? 0.f : cst[ci];
        float si = 1.f / (1.f + expf(-gi));
        float sf = 1.f / (1.f + expf(-gf));
        float so = 1.f / (1.f + expf(-go));
        float cn = sf * cprev + si * tanhf(gg);
        cst[ci] = cn;
        float hv = so * tanhf(cn);
        float* hout = layer ? h1seq : h0seq;
        hout[((size_t)tt * 8 + b) * 512 + ji] = hv;
        if (layer) h1b[((size_t)tt * 8 + b) * 512 + ji] = (u16)f2bf_rne(hv);
    }
}

// ======================= banded attention (radius 50) =======================
__global__ __launch_bounds__(128) void attn_kernel(const float* __restrict__ q,
                                                   const float* __restrict__ k,
                                                   const float* __restrict__ cnt,
                                                   const float* __restrict__ rel,
                                                   float* __restrict__ out)
{
    int t = blockIdx.x, h = blockIdx.y, b = blockIdx.z;
    int s_lo = max(0, t - R_), s_hi = min(L_ - 1, t + R_);
    int W = s_hi - s_lo + 1;
    int tid = threadIdx.x;

    __shared__ float qrow[64];
    __shared__ float dots[104];
    __shared__ float red[128];

    const float* qp = q + ((size_t)(b * L_ + t) * C_ + h * D_);
    if (tid < 64) qrow[tid] = qp[tid];
    __syncthreads();

    if (tid < W) {
        int s = s_lo + tid;
        const float* kp = k + ((size_t)(b * L_ + s) * C_ + h * D_);
        const float* rp = rel + (R_ + t - s) * D_;
        float acc = 0.f;
#pragma unroll 8
        for (int d = 0; d < 64; ++d)
            acc += qrow[d] * (kp[d] + 0.3f * rp[d]);
        dots[tid] = acc;
    }
    __syncthreads();

    red[tid] = (tid < W) ? dots[tid] : -INFINITY;
    __syncthreads();
    for (int s = 64; s > 0; s >>= 1) {
        if (tid < s) red[tid] = fmaxf(red[tid], red[tid + s]);
        __syncthreads();
    }
    float mx = red[0];
    __syncthreads();
    float e = 0.f;
    if (tid < W) { e = expf(dots[tid] - mx); dots[tid] = e; }
    red[tid] = e;
    __syncthreads();
    for (int s = 64; s > 0; s >>= 1) {
        if (tid < s) red[tid] += red[tid + s];
        __syncthreads();
    }
    float inv = 1.f / red[0];
    if (tid < W) dots[tid] *= inv;
    __syncthreads();

    if (tid < 64) {
        float acc = 0.f;
        const float* cb = cnt + ((size_t)(b * L_ + s_lo) * C_ + h * D_ + tid);
        const float* rb = rel + (R_ + t - s_lo) * D_ + tid;
        for (int i = 0; i < W; ++i)
            acc += dots[i] * (cb[(size_t)i * C_] + 0.3f * rb[-i * D_]);
        out[(size_t)(b * L_ + t) * C_ + h * D_ + tid] = acc;
    }
}

// ======================= BatchNorm sums (coalesced, atomic) =======================
__global__ __launch_bounds__(512) void bn_sum(const float* __restrict__ fcout, float* __restrict__ stats)
{
    int c = threadIdx.x;          // 512 threads = one per channel
    float s = 0.f, ss = 0.f;
    for (int m = blockIdx.x; m < M_; m += 32) {
        float v = fcout[(size_t)m * 512 + c];
        s += v; ss += v * v;
    }
    atomicAdd(&stats[c], s);
    atomicAdd(&stats[512 + c], ss);
}

// ======================= BN apply + ReLU*scale + residual =======================
__global__ __launch_bounds__(256) void bn_apply(const float* __restrict__ fcout,
                                                const float* __restrict__ stats,
                                                const float* __restrict__ bng, const float* __restrict__ bnb,
                                                const float* __restrict__ ascl,
                                                const float* __restrict__ h1tm,
                                                float* __restrict__ xfin)
{
    int idx = blockIdx.x * 256 + threadIdx.x;
    if (idx >= M_ * 512) return;
    int c = idx & 511;
    int m = idx >> 9;
    int b = m / L_, t = m - b * L_;
    float mean = stats[c] * (1.f / (float)M_);
    float var = stats[512 + c] * (1.f / (float)M_) - mean * mean;
    float rs = rsqrtf(fmaxf(var, 0.f) + 1e-5f);
    float v = (fcout[idx] - mean) * rs * bng[c] + bnb[c];
    v = fmaxf(v, 0.f) * ascl[c];
    xfin[idx] = h1tm[((size_t)(t * 8 + b)) * 512 + c] + v;
}

// ======================= host launch =======================
extern "C" void kernel_launch(void* const* d_in, const int* in_sizes, int n_in,
                              void* d_out, int out_size, void* d_ws, size_t ws_size,
                              hipStream_t stream)
{
    const float* meg  = (const float*)d_in[0];
    const float* w1   = (const float*)d_in[1];
    const float* b1   = (const float*)d_in[2];
    const float* w2   = (const float*)d_in[3];
    const float* b2   = (const float*)d_in[4];
    const float* semb = (const float*)d_in[5];
    const float* Wih0 = (const float*)d_in[6];
    const float* Whh0 = (const float*)d_in[7];
    const float* bih0 = (const float*)d_in[8];
    const float* bhh0 = (const float*)d_in[9];
    const float* Wih1 = (const float*)d_in[10];
    const float* Whh1 = (const float*)d_in[11];
    const float* bih1 = (const float*)d_in[12];
    const float* bhh1 = (const float*)d_in[13];
    const float* qw   = (const float*)d_in[14];
    const float* qb   = (const float*)d_in[15];
    const float* kw   = (const float*)d_in[16];
    const float* kb   = (const float*)d_in[17];
    const float* cw   = (const float*)d_in[18];
    const float* cbi  = (const float*)d_in[19];
    const float* rel  = (const float*)d_in[20];
    const float* fcw  = (const float*)d_in[21];
    const float* fcb  = (const float*)d_in[22];
    const float* bng  = (const float*)d_in[23];
    const float* bnb  = (const float*)d_in[24];
    const float* ascl = (const float*)d_in[25];
    const float* outw = (const float*)d_in[26];
    const float* outb = (const float*)d_in[27];
    const int* subj = (const int*)d_in[28];
    float* out = (float*)d_out;

    float* ws = (float*)d_ws;
    // ---- arena (float-slot offsets), phase-overlaid ----
    // conv phase:
    u16*   x1b   = (u16*)(ws + 0);          // [8200][512] bf16 -> 2,099,200 slots
    u32*   w1p   = (u32*)(ws + 6562304);    // 512x546  -> ends 6,841,856 (in dead pre0 region)
    u32*   w2p   = (u32*)(ws + 6841856);    // 512x1024 -> ends 7,366,144
    u16*   x2b   = (u16*)(ws + 4198400);    // [4104][576] bf16 -> 1,181,952 slots, ends 5,380,352
    u32*   wih0p = (u32*)(ws + 14967296);   // 2048x288 -> ends 15,557,120 (in dead h0 region)
    // LSTM phase:
    u32*   P0    = (u32*)(ws + 0);          // 524,288 (over dead x1b)
    u32*   P1    = (u32*)(ws + 524288);
    u32*   P2    = (u32*)(ws + 1048576);
    float* c0    = ws + 1572864;
    float* c1    = ws + 1576960;
    float* pre0  = ws + 6562304;            // [(t*8+b)][2048] fp32 -> 14,967,296
    float* h0    = ws + 14967296;           // [t][b][c] fp32 -> 17,068,544
    float* h1    = ws + 17068544;           // -> 19,169,792
    u16*   h1b   = (u16*)(ws + 19169792);   // bf16 mirror -> 1,050,624 slots, ends 20,220,416
    // post-LSTM phase:
    float* qb_f  = ws + 0;                  // 2,101,248
    float* kb_f  = ws + 2101248;
    float* cb_f  = ws + 4202496;
    float* attno = ws + 6562304;            // over dead pre0
    float* fco   = ws + 8663552;
    float* stats = ws + 10764800;           // 1024
    u32*   qwp   = (u32*)(ws + 10765824);   // 131,072
    u32*   kwp   = (u32*)(ws + 10896896);
    u32*   cwp   = (u32*)(ws + 11027968);
    u32*   fcwp  = (u32*)(ws + 11159040);
    u32*   outwp = (u32*)(ws + 11290112);   // 32,768 -> ends 11,322,880
    float* xfin  = ws + 19169792;           // overwrites dead h1b at bn_apply time

    auto gemm = [&](const void* A, const u32* Bp, const float* bi1, const float* bi2,
                    float* Cf, u16* Cb, int Msz, int Nsz, int Ksz,
                    int lda, int ldc, int amode, int cmode, int relu) {
        dim3 g((Msz + 63) / 64, Nsz / 64);
        gemm_kernel<<<g, 256, 0, stream>>>(A, Bp, bi1, bi2, Cf, Cb,
                                           Msz, Nsz, Ksz, lda, ldc, amode, cmode, relu);
    };

    // ---- pack conv weights ----
    pack_b<<<(512 * 546 + 255) / 256, 256, 0, stream>>>(w1, w1p, 512, 1092);
    pack_w2k<<<2048, 256, 0, stream>>>(w2, w2p);

    // conv1 -> x1b bf16 [b*1025+t][512], relu
    gemm(meg, w1p, b1, nullptr, nullptr, x1b, M1_, 512, K1_, 0, 512, 2, 3, 1);
    // conv2 -> x2b bf16 [b*513+t][576] cols 0..511, relu (k-order kk*512+ci)
    gemm(x1b, w2p, b2, nullptr, nullptr, x2b, M_, 512, 2048, 0, CE_, 5, 3, 1);
    // subject embedding bf16 -> cols 512..575
    emb_kernel<<<(M_ * 64 + 255) / 256, 256, 0, stream>>>(semb, subj, x2b);

    // ---- pack LSTM + pre0 weights ----
    pack_w<<<2048, 256, 0, stream>>>(Whh0, P0);
    pack_w<<<2048, 256, 0, stream>>>(Wih1, P1);
    pack_w<<<2048, 256, 0, stream>>>(Whh1, P2);
    pack_b<<<(2048 * 288 + 255) / 256, 256, 0, stream>>>(Wih0, wih0p, 2048, 576);

    // layer-0 x-projection (bf16 A, packed B, time-major fp32 out, both biases)
    gemm(x2b, wih0p, bih0, bhh0, pre0, nullptr, M_, 2048, CE_, CE_, 2048, 6, 2, 0);

    // fused 2-layer LSTM: 514 launches (R10 structure)
    for (int t = 0; t <= L_; ++t)
        lstm_step_fused<<<256, 256, 0, stream>>>(pre0, P0, P1, P2, bih1, bhh1,
                                                 h0, h1, h1b, c0, c1, t);

    // ---- pack post weights (pre0 region now dead) ----
    pack_b<<<512, 256, 0, stream>>>(qw, qwp, 512, 512);
    pack_b<<<512, 256, 0, stream>>>(kw, kwp, 512, 512);
    pack_b<<<512, 256, 0, stream>>>(cw, cwp, 512, 512);
    pack_b<<<512, 256, 0, stream>>>(fcw, fcwp, 512, 512);
    pack_b<<<128, 256, 0, stream>>>(outw, outwp, 128, 512);
    hipMemsetAsync(stats, 0, 1024 * sizeof(float), stream);

    // fused q/k/cnt projections (bf16 h1b)
    gemm_qkv<<<dim3((M_ + 63) / 64, 24), 256, 0, stream>>>(h1b, qwp, kwp, cwp, qb, kb, cbi,
                                                           qb_f, kb_f, cb_f);

    attn_kernel<<<dim3(L_, H_, B_), 128, 0, stream>>>(qb_f, kb_f, cb_f, rel, attno);

    // fc + BN(train) + relu*scale + residual -> xfin
    gemm(attno, fcwp, fcb, nullptr, fco, nullptr, M_, 512, 512, 512, 512, 0, 0, 0);
    bn_sum<<<32, 512, 0, stream>>>(fco, stats);
    bn_apply<<<(M_ * 512 + 255) / 256, 256, 0, stream>>>(fco, stats, bng, bnb, ascl, h1, xfin);

    // final projection -> d_out [b][128][t] fp32
    gemm(xfin, outwp, outb, nullptr, out, nullptr, M_, 128, 512, 512, 0, 0, 1, 0);
}